// Round 16
// baseline (129.560 us; speedup 1.0000x reference)
//
#include <hip/hip_runtime.h>

typedef __bf16 bf16;
typedef __bf16 bf16x4 __attribute__((ext_vector_type(4)));
typedef __bf16 bf16x8 __attribute__((ext_vector_type(8)));
typedef float f32x4 __attribute__((ext_vector_type(4)));

#define MFMA16(a, b, c) __builtin_amdgcn_mfma_f32_16x16x32_bf16((a), (b), (c), 0, 0, 0)

constexpr int B_ = 2, S_ = 2048, D_ = 1024, H_ = 16, DK_ = 64;

__device__ __forceinline__ void gload16(const bf16* g, bf16* l)
{
  __builtin_amdgcn_global_load_lds(
      (const __attribute__((address_space(1))) uint32_t*)g,
      (__attribute__((address_space(3))) uint32_t*)l, 16, 0, 0);
}

// ---------------------------------------------------------------------------
// Convert f32 inputs (x + 4 weights) to bf16 workspace images.
// ---------------------------------------------------------------------------
__global__ __launch_bounds__(256) void cvt_k(
    const float* __restrict__ x, const float* __restrict__ Wq, const float* __restrict__ Wk,
    const float* __restrict__ Wv, const float* __restrict__ Wo, bf16* __restrict__ ws)
{
  size_t f = ((size_t)blockIdx.x * 256 + threadIdx.x) * 4;
  const float* src;
  bf16* dst;
  size_t off;
  if (f < 4194304) {
    src = x; dst = ws; off = f;
  } else {
    size_t g = f - 4194304;
    int wsel = (int)(g >> 20);
    off = g & 1048575;
    src = wsel == 0 ? Wq : wsel == 1 ? Wk : wsel == 2 ? Wv : Wo;
    dst = ws + 4194304 + ((size_t)wsel << 20);
  }
  float4 v = *(const float4*)(src + off);
  bf16x4 o = {(bf16)v.x, (bf16)v.y, (bf16)v.z, (bf16)v.w};
  *(bf16x4*)(dst + off) = o;
}

// ---------------------------------------------------------------------------
// 128x128-tile GEMM, BK=64, 4 waves (2x2), 64x64 acc per wave (m97 structure).
// ---------------------------------------------------------------------------
template <typename TY, int PERM>
__global__ __launch_bounds__(256) void gemm_k(
    const bf16* __restrict__ A,
    const bf16* __restrict__ W0, const bf16* __restrict__ W1, const bf16* __restrict__ W2,
    TY* __restrict__ Y0, TY* __restrict__ Y1, TY* __restrict__ Y2,
    int Kdim, float scale0)
{
  __shared__ __align__(16) bf16 As[128 * 64];
  __shared__ __align__(16) bf16 Bs[128 * 64];
  const int t = threadIdx.x, l = t & 63, w = t >> 6;
  const int wm = w >> 1, wn = w & 1;
  const int m0 = blockIdx.x * 128, n0 = blockIdx.y * 128;
  const int z = blockIdx.z;
  const bf16* W = z == 0 ? W0 : z == 1 ? W1 : W2;
  TY* Y = z == 0 ? Y0 : z == 1 ? Y1 : Y2;
  const float scale = (PERM == 1 && z == 0) ? scale0 : 1.0f;

  f32x4 acc[4][4] = {};

  for (int k0 = 0; k0 < Kdim; k0 += 64) {
    __syncthreads();
#pragma unroll
    for (int j = 0; j < 4; ++j) {
      int slot = j * 256 + t;
      int row = slot >> 3, c8 = slot & 7;
      int csw = (c8 ^ (row & 7)) << 3;
      gload16(A + (size_t)(m0 + row) * Kdim + k0 + csw, &As[(j * 256 + w * 64) * 8]);
      gload16(W + (size_t)(n0 + row) * Kdim + k0 + csw, &Bs[(j * 256 + w * 64) * 8]);
    }
    asm volatile("s_waitcnt vmcnt(0)" ::: "memory");
    __syncthreads();
#pragma unroll
    for (int kk = 0; kk < 2; ++kk) {
      bf16x8 af[4], bfr[4];
#pragma unroll
      for (int i = 0; i < 4; ++i) {
        int Ra = wm * 64 + i * 16 + (l & 15);
        int Rb = wn * 64 + i * 16 + (l & 15);
        int c = kk * 4 + (l >> 4);
        af[i] = *(const bf16x8*)&As[Ra * 64 + ((c ^ (Ra & 7)) << 3)];
        bfr[i] = *(const bf16x8*)&Bs[Rb * 64 + ((c ^ (Rb & 7)) << 3)];
      }
#pragma unroll
      for (int mi = 0; mi < 4; ++mi)
#pragma unroll
        for (int ni = 0; ni < 4; ++ni)
          acc[mi][ni] = MFMA16(af[mi], bfr[ni], acc[mi][ni]);
    }
  }

#pragma unroll
  for (int mi = 0; mi < 4; ++mi)
#pragma unroll
    for (int ni = 0; ni < 4; ++ni)
#pragma unroll
      for (int j = 0; j < 4; ++j) {
        int m = m0 + wm * 64 + mi * 16 + (l >> 4) * 4 + j;
        int n = n0 + wn * 64 + ni * 16 + (l & 15);
        float v = acc[mi][ni][j] * scale;
        if (PERM == 0) {
          Y[(size_t)m * 1024 + n] = (TY)v;
        } else {
          int b = m >> 11, s = m & (S_ - 1), h = n >> 6, d = n & (DK_ - 1);
          Y[(((size_t)(b * H_ + h)) * S_ + s) * DK_ + d] = (TY)v;
        }
      }
}

// ---------------------------------------------------------------------------
// RoPE in-place on K only (Q rope is fused into the attention prologue).
// One thread = 8 pairs (32B load/store).
// ---------------------------------------------------------------------------
__global__ __launch_bounds__(256) void rope_k(
    bf16* __restrict__ K, const int* __restrict__ pos)
{
  int idx = blockIdx.x * 256 + threadIdx.x;        // 262144 threads
  int kpg = idx & 3;                               // 16-elem group along d
  int s = (idx >> 2) & (S_ - 1);
  int bh = idx >> 13;                              // 0..31
  float p = (float)pos[s];
  size_t off = ((size_t)bh * S_ + s) * DK_ + kpg * 16;
  bf16x8 lo = *(const bf16x8*)(K + off);
  bf16x8 hi = *(const bf16x8*)(K + off + 8);
  bf16x8 olo, ohi;
#pragma unroll
  for (int ii = 0; ii < 8; ++ii) {
    int kp = kpg * 8 + ii;
    float ang = p * exp2f((float)kp * -0.41524101186017f);  // log2(10000)/32
    float sn, cs;
    __sincosf(ang, &sn, &cs);
    float x0 = (float)((ii < 4 ? lo : hi)[(ii & 3) * 2]);
    float x1 = (float)((ii < 4 ? lo : hi)[(ii & 3) * 2 + 1]);
    bf16 o0 = (bf16)(x0 * cs - x1 * sn);
    bf16 o1 = (bf16)(x0 * sn + x1 * cs);
    if (ii < 4) { olo[(ii & 3) * 2] = o0; olo[(ii & 3) * 2 + 1] = o1; }
    else        { ohi[(ii & 3) * 2] = o0; ohi[(ii & 3) * 2 + 1] = o1; }
  }
  *(bf16x8*)(K + off) = olo;
  *(bf16x8*)(K + off + 8) = ohi;
}

// ---------------------------------------------------------------------------
// QBLK=128 causal flash attention: 8 waves, wave w owns q-rows [w*16, w*16+16)
// of a 128-row q-tile. One K/V staging serves all 128 rows (halved staging).
// No-max softmax (lsum deferred to epilogue), Q-rope fused in prologue.
// Grid 512 = (qt-pair balanced, bh); 2 blocks/CU (LDS = 49152 B).
// ---------------------------------------------------------------------------
__global__ __launch_bounds__(512, 2) void attn_k(
    const bf16* __restrict__ Q, const bf16* __restrict__ K, const bf16* __restrict__ V,
    const int* __restrict__ pos, bf16* __restrict__ O)
{
  __shared__ __align__(16) bf16 Klds[2][64 * 64];   // 16384 B
  __shared__ __align__(16) bf16 Vt[2][64 * 64];     // 16384 B, swizzled [d][kv]
  __shared__ __align__(16) bf16 Ps[8][16 * 64];     // 16384 B, swizzled per wave

  const int t = threadIdx.x, l = t & 63, w = t >> 6;  // w 0..7
  const int wl = w & 3;
  const int bx = blockIdx.x;
  const int i5 = bx >> 5;                    // 0..15
  const int bh = bx & 31;
  const int a = i5 & 7, bq = i5 >> 3;        // bq 0..1
  const int qt2 = bq ? a : (15 - a);         // 128-row q-tile; co-resident blocks complementary
  const int b = bh >> 4, h = bh & 15;
  const size_t base = (size_t)bh * S_ * DK_;
  const int q0 = qt2 * 128;
  const int ntk = 2 * qt2 + 2;               // kv tiles 0 .. 2*qt2+1
  const int myqt = 2 * qt2 + (w >> 2);       // this wave's diagonal tile

  // Q fragments + fused RoPE (Q pre-scaled by log2e/8 in projection epilogue)
  const int qrow = w * 16 + (l & 15), qcol = (l >> 4) * 8;
  const bf16* pq = Q + base + (size_t)(q0 + qrow) * 64 + qcol;
  bf16x8 aq0 = *(const bf16x8*)pq, aq1 = *(const bf16x8*)(pq + 32);
  {
    float p = (float)pos[q0 + qrow];
#pragma unroll
    for (int i2 = 0; i2 < 4; ++i2) {
      int kp = (l >> 4) * 4 + i2;
      float s0, c0, s1, c1;
      __sincosf(p * exp2f((float)kp * -0.41524101186017f), &s0, &c0);
      __sincosf(p * exp2f((float)(kp + 16) * -0.41524101186017f), &s1, &c1);
      float x0 = (float)aq0[2 * i2], x1 = (float)aq0[2 * i2 + 1];
      aq0[2 * i2] = (bf16)(x0 * c0 - x1 * s0);
      aq0[2 * i2 + 1] = (bf16)(x0 * s0 + x1 * c0);
      x0 = (float)aq1[2 * i2]; x1 = (float)aq1[2 * i2 + 1];
      aq1[2 * i2] = (bf16)(x0 * c1 - x1 * s1);
      aq1[2 * i2 + 1] = (bf16)(x0 * s1 + x1 * c1);
    }
  }

  // prologue: stage K[0] (1 gload16/thread) + V[0] (8 elems/thread, transposed)
  {
    int row = t >> 3, c8 = t & 7;
    gload16(K + base + (size_t)row * 64 + ((c8 ^ (row & 7)) << 3),
            &Klds[0][(w * 64) * 8]);
    const bf16* pv = V + base + (size_t)l * 64 + w * 8;
    bf16x8 v0 = *(const bf16x8*)pv;
    asm volatile("s_waitcnt vmcnt(0)" ::: "memory");
#pragma unroll
    for (int ii = 0; ii < 8; ++ii) {
      int d0 = w * 8 + ii;
      Vt[0][d0 * 64 + (((l >> 3) ^ (d0 & 7)) << 3) + (l & 7)] = v0[ii];
    }
  }
  __syncthreads();

  f32x4 acc[4] = {};
  float lsum[4] = {0.f, 0.f, 0.f, 0.f};   // in-lane partial row-sums

  int cur = 0;
  for (int tk = 0; tk < ntk; ++tk) {
    const int nxt = cur ^ 1;
    const bool hasn = (tk + 1) < ntk;
    bf16x8 v0;
    if (hasn) {  // issue next tile's loads before compute
      const int kv0n = (tk + 1) * 64;
      int row = t >> 3, c8 = t & 7;
      gload16(K + base + (size_t)(kv0n + row) * 64 + ((c8 ^ (row & 7)) << 3),
              &Klds[nxt][(w * 64) * 8]);
      v0 = *(const bf16x8*)(V + base + (size_t)(kv0n + l) * 64 + w * 8);
    }

    if (tk <= myqt) {
      // S = Q K^T (16 q-rows x 64 kv per wave), swizzled K reads
      f32x4 sc[4];
      __builtin_amdgcn_s_setprio(1);
#pragma unroll
      for (int nf = 0; nf < 4; ++nf) {
        int R = nf * 16 + (l & 15);
        int c0 = l >> 4;
        bf16x8 b0 = *(const bf16x8*)&Klds[cur][R * 64 + ((c0 ^ (R & 7)) << 3)];
        bf16x8 b1 = *(const bf16x8*)&Klds[cur][R * 64 + (((4 + c0) ^ (R & 7)) << 3)];
        f32x4 s = {};
        s = MFMA16(aq0, b0, s);
        s = MFMA16(aq1, b1, s);
        sc[nf] = s;
      }
      __builtin_amdgcn_s_setprio(0);

      if (tk == myqt) {  // causal mask: q_local - tk*64 = wl*16 + r
#pragma unroll
        for (int nf = 0; nf < 4; ++nf)
#pragma unroll
          for (int j = 0; j < 4; ++j) {
            int kvl = nf * 16 + (l & 15);
            int ql = wl * 16 + (l >> 4) * 4 + j;
            if (kvl > ql) sc[nf][j] = -1e30f;
          }
      }

      // no-max softmax numerator: p = exp2(sc); masked -> exp2(-1e30) = 0.
#pragma unroll
      for (int nf = 0; nf < 4; ++nf)
#pragma unroll
        for (int j = 0; j < 4; ++j) {
          float p = exp2f(sc[nf][j]);
          lsum[j] += p;
          int r = (l >> 4) * 4 + j, c = nf * 16 + (l & 15);
          Ps[w][r * 64 + ((((c >> 3) ^ (r & 7))) << 3) + (c & 7)] = (bf16)p;
        }

      // our Ps writes visible to our reads
      asm volatile("s_waitcnt lgkmcnt(0)" ::: "memory");

      // O += P V (swizzled Ps + Vt reads)
      __builtin_amdgcn_s_setprio(1);
#pragma unroll
      for (int kk = 0; kk < 2; ++kk) {
        int rp = l & 15;
        int c8p = kk * 4 + (l >> 4);
        bf16x8 ap = *(const bf16x8*)&Ps[w][rp * 64 + ((c8p ^ (rp & 7)) << 3)];
#pragma unroll
        for (int nf = 0; nf < 4; ++nf) {
          int R = nf * 16 + (l & 15);
          bf16x8 bv = *(const bf16x8*)&Vt[cur][R * 64 + ((c8p ^ (R & 7)) << 3)];
          acc[nf] = MFMA16(ap, bv, acc[nf]);
        }
      }
      __builtin_amdgcn_s_setprio(0);
    }

    if (hasn) {  // land next V into the other buffer (conflict-free swizzled writes)
#pragma unroll
      for (int ii = 0; ii < 8; ++ii) {
        int d0 = w * 8 + ii;
        Vt[nxt][d0 * 64 + (((l >> 3) ^ (d0 & 7)) << 3) + (l & 7)] = v0[ii];
      }
      asm volatile("s_waitcnt vmcnt(0)" ::: "memory");  // K[nxt] landed
    }
    __syncthreads();
    cur = nxt;
  }

  // epilogue: single cross-lane lsum reduction, normalize, write O
#pragma unroll
  for (int m = 1; m <= 8; m <<= 1)
#pragma unroll
    for (int j = 0; j < 4; ++j)
      lsum[j] += __shfl_xor(lsum[j], m, 64);

#pragma unroll
  for (int nf = 0; nf < 4; ++nf)
#pragma unroll
    for (int j = 0; j < 4; ++j) {
      int r = w * 16 + (l >> 4) * 4 + j;
      int d = nf * 16 + (l & 15);
      O[((size_t)(b * S_ + q0 + r) * H_ + h) * DK_ + d] = (bf16)(acc[nf][j] / lsum[j]);
    }
}

// ---------------------------------------------------------------------------
extern "C" void kernel_launch(void* const* d_in, const int* in_sizes, int n_in,
                              void* d_out, int out_size, void* d_ws, size_t ws_size,
                              hipStream_t stream)
{
  const float* x = (const float*)d_in[0];
  const float* Wq = (const float*)d_in[1];
  const float* Wk = (const float*)d_in[2];
  const float* Wv = (const float*)d_in[3];
  const float* Wo = (const float*)d_in[4];
  const int* pos = (const int*)d_in[5];

  bf16* ws = (bf16*)d_ws;
  const size_t NE = (size_t)B_ * H_ * S_ * DK_;  // 4,194,304
  bf16* xb = ws;
  bf16* Wqb = ws + NE;
  bf16* Wkb = Wqb + 1048576;
  bf16* Wvb = Wkb + 1048576;
  bf16* Wob = Wvb + 1048576;
  bf16* Qb = Wob + 1048576;
  bf16* Kb = Qb + NE;
  bf16* Vb = Kb + NE;
  bf16* Ob = xb;  // x dead after QKV projections

  dim3 blk(256);

  hipLaunchKernelGGL(cvt_k, dim3(8192), blk, 0, stream, x, Wq, Wk, Wv, Wo, ws);

  // Q prescale folds 1/sqrt(DK) * log2(e) so attention can use exp2 directly
  hipLaunchKernelGGL((gemm_k<bf16, 1>), dim3(32, 8, 3), blk, 0, stream,
                     xb, Wqb, Wkb, Wvb, Qb, Kb, Vb, 1024, 0.125f * 1.4426950408889634f);

  // RoPE on K only (Q rope fused into attention prologue)
  hipLaunchKernelGGL(rope_k, dim3(1024), blk, 0, stream, Kb, pos);

  // QBLK=128 8-wave causal flash attention (grid 512, 2 blocks/CU)
  hipLaunchKernelGGL(attn_k, dim3(512), dim3(512), 0, stream, Qb, Kb, Vb, pos, Ob);

  hipLaunchKernelGGL((gemm_k<float, 0>), dim3(32, 8, 1), blk, 0, stream,
                     Ob, Wob, Wob, Wob, (float*)d_out, (float*)d_out, (float*)d_out,
                     1024, 1.0f);
}